// Round 6
// baseline (779.224 us; speedup 1.0000x reference)
//
#include <hip/hip_runtime.h>
#include <math.h>

#define NN      100000
#define EE      1600000
#define NPAIRS  800000
#define DIN     128
#define CC      16
#define NITERS  5
#define PPT     4                    // pairs per thread
#define NGRP    (NPAIRS / PPT)       // 200000 groups of 16 lanes
#define NBLK    ((NN + 255) / 256)   // 391 scan blocks
#define NEGLOGC (-2.772588722239781f)

typedef float  f4 __attribute__((ext_vector_type(4)));
typedef int    i2 __attribute__((ext_vector_type(2)));

// ---------------------------------------------------------------------------
// helpers: bf16 <-> f32
// ---------------------------------------------------------------------------
__device__ __forceinline__ unsigned short f2bf(float f) {
    unsigned int u = __float_as_uint(f);
    unsigned int r = u + 0x7fffu + ((u >> 16) & 1u);   // round-nearest-even
    return (unsigned short)(r >> 16);
}
__device__ __forceinline__ float bf2f(unsigned short u) {
    return __uint_as_float((unsigned int)u << 16);
}

// ---------------------------------------------------------------------------
// fused setup: M = sigmoid(10*param); logb0 = log_softmax(x@W+b);
// dst-degree histogram (deg must be memset to 0 beforehand).
// grid = 6250 blocks of 256 (covers NN*CC == EE == 1.6M exactly)
// ---------------------------------------------------------------------------
__global__ __launch_bounds__(256) void k_setup(
    const float* __restrict__ x, const float* __restrict__ W,
    const float* __restrict__ b, const float* __restrict__ param,
    const int* __restrict__ edst,
    float* __restrict__ M, float* __restrict__ logb0,
    unsigned int* __restrict__ deg)
{
    if (blockIdx.x == 0 && threadIdx.x < CC * (CC + 1) / 2) {
        int i = threadIdx.x;
        int r = 0;
        while ((r + 1) * (r + 2) / 2 <= i) ++r;
        int c = i - r * (r + 1) / 2;
        float z = param[i] * 10.0f;
        float s = 1.0f / (1.0f + __expf(-z));
        M[r * CC + c] = s;
        if (r != c) M[c * CC + r] = s;
    }

    int idx = blockIdx.x * 256 + threadIdx.x;

    // degree histogram for CSR (idx == edge id; grid covers EE exactly)
    atomicAdd(&deg[edst[idx]], 1u);

    int node = idx >> 4;
    int cls  = idx & 15;
    const f4* xr4 = (const f4*)(x + (long)node * DIN);
    float acc = b[cls];
#pragma unroll 8
    for (int k4 = 0; k4 < DIN / 4; ++k4) {
        f4 xv = __builtin_nontemporal_load(xr4 + k4);
        acc = fmaf(xv.x, W[(4 * k4 + 0) * CC + cls], acc);
        acc = fmaf(xv.y, W[(4 * k4 + 1) * CC + cls], acc);
        acc = fmaf(xv.z, W[(4 * k4 + 2) * CC + cls], acc);
        acc = fmaf(xv.w, W[(4 * k4 + 3) * CC + cls], acc);
    }
    float m = acc;
    for (int off = 8; off; off >>= 1) m = fmaxf(m, __shfl_xor(m, off, 16));
    float s = __expf(acc - m);
    for (int off = 8; off; off >>= 1) s += __shfl_xor(s, off, 16);
    logb0[idx] = acc - m - __logf(s);
}

// ---------------------------------------------------------------------------
// CSR build: 2-level exclusive scan of deg -> row, then scatter edge ids
// ---------------------------------------------------------------------------
__global__ __launch_bounds__(256) void k_scan_blk(
    const unsigned int* __restrict__ deg, unsigned int* __restrict__ rowtmp,
    unsigned int* __restrict__ bsum)
{
    __shared__ unsigned int s[256];
    int t = threadIdx.x, i = blockIdx.x * 256 + t;
    unsigned int v = (i < NN) ? deg[i] : 0u;
    s[t] = v; __syncthreads();
    for (int off = 1; off < 256; off <<= 1) {
        unsigned int a = (t >= off) ? s[t - off] : 0u;
        __syncthreads();
        s[t] += a;
        __syncthreads();
    }
    if (i < NN) rowtmp[i] = s[t] - v;           // exclusive within block
    if (t == 255) bsum[blockIdx.x] = s[255];    // block total
}

__global__ __launch_bounds__(512) void k_scan_top(
    const unsigned int* __restrict__ bsum, unsigned int* __restrict__ boff)
{
    __shared__ unsigned int s[512];
    int t = threadIdx.x;
    unsigned int v = (t < NBLK) ? bsum[t] : 0u;
    s[t] = v; __syncthreads();
    for (int off = 1; off < 512; off <<= 1) {
        unsigned int a = (t >= off) ? s[t - off] : 0u;
        __syncthreads();
        s[t] += a;
        __syncthreads();
    }
    boff[t] = s[t] - v;                         // exclusive block offsets
}

__global__ __launch_bounds__(256) void k_scan_add(
    const unsigned int* __restrict__ rowtmp, const unsigned int* __restrict__ boff,
    unsigned int* __restrict__ row, unsigned int* __restrict__ cursor)
{
    int i = blockIdx.x * 256 + threadIdx.x;
    if (i < NN) {
        unsigned int r = rowtmp[i] + boff[blockIdx.x];
        row[i]    = r;
        cursor[i] = r;
    }
    if (i == 0) row[NN] = EE;
}

__global__ __launch_bounds__(256) void k_csrscat(
    const int* __restrict__ edst, unsigned int* __restrict__ cursor,
    unsigned int* __restrict__ csr)
{
    int e = blockIdx.x * 256 + threadIdx.x;     // grid covers EE exactly
    int d = edst[e];
    unsigned int pos = atomicAdd(&cursor[d], 1u);
    csr[pos] = (unsigned int)e;
}

// ---------------------------------------------------------------------------
// message update (NO scatter, NO atomics). 16 lanes per edge-pair (lane =
// class). Linear-space matvec:
//   S[c] = sum_k exp(t[k]) * M[k][c];  log_msg[c] = log S[c] - log(sum_c S[c])
// t in [-log C, ~7] -> exp fp32-safe, S >= ~6e-4; no max-subtraction needed.
// msg[e*16+c] holds edge e's message as bf16 (32B rows; pair = 64B line).
// RD_MSG=false on iter 0 (msg == const -log C; never materialized).
// ---------------------------------------------------------------------------
template <bool RD_MSG>
__global__ __launch_bounds__(256) void k_edges_t(
    const i2* __restrict__ esrc2,
    const float* __restrict__ logb, const float* __restrict__ Mg,
    unsigned short* __restrict__ msg)
{
    __shared__ float sM[CC * CC];
    __shared__ float sE[PPT][16 * 40];   // per-r slice, per-group stride 40
    sM[threadIdx.x] = Mg[threadIdx.x];   // blockDim == 256
    __syncthreads();

    const int lane = threadIdx.x & 15;
    const int gl   = threadIdx.x >> 4;           // group within block (0..15)
    const int g    = blockIdx.x * 16 + gl;       // global group

    float Hrow[CC];                              // M[k][lane] (symmetric)
#pragma unroll
    for (int k = 0; k < CC; ++k) Hrow[k] = sM[k * CC + lane];

    i2 s01[PPT];
    unsigned short m0[PPT], m1[PPT];
#pragma unroll
    for (int r = 0; r < PPT; ++r) {
        int p = g + r * NGRP;
        s01[r] = __builtin_nontemporal_load(esrc2 + p);
        if (RD_MSG) {
            m0[r] = __builtin_nontemporal_load(msg + (long)(2 * p)     * CC + lane);
            m1[r] = __builtin_nontemporal_load(msg + (long)(2 * p + 1) * CC + lane);
        }
    }

#pragma unroll
    for (int r = 0; r < PPT; ++r) {
        float lb0 = logb[(long)s01[r].x * CC + lane];
        float lb1 = logb[(long)s01[r].y * CC + lane];
        float mo0 = RD_MSG ? bf2f(m0[r]) : NEGLOGC;
        float mo1 = RD_MSG ? bf2f(m1[r]) : NEGLOGC;
        float* eb = sE[r] + gl * 40;
        eb[lane]      = __expf(lb0 - mo1);   // t = logb[src] - msg[reverse]
        eb[16 + lane] = __expf(lb1 - mo0);
    }

#pragma unroll
    for (int r = 0; r < PPT; ++r) {
        const float* eb = sE[r] + gl * 40;
        float ev0[CC], ev1[CC];
        *(float4*)(ev0 +  0) = *(const float4*)(eb +  0);
        *(float4*)(ev0 +  4) = *(const float4*)(eb +  4);
        *(float4*)(ev0 +  8) = *(const float4*)(eb +  8);
        *(float4*)(ev0 + 12) = *(const float4*)(eb + 12);
        *(float4*)(ev1 +  0) = *(const float4*)(eb + 16);
        *(float4*)(ev1 +  4) = *(const float4*)(eb + 20);
        *(float4*)(ev1 +  8) = *(const float4*)(eb + 24);
        *(float4*)(ev1 + 12) = *(const float4*)(eb + 28);

        float S0 = 0.f, S1 = 0.f;
#pragma unroll
        for (int k = 0; k < CC; ++k) {
            S0 = fmaf(ev0[k], Hrow[k], S0);
            S1 = fmaf(ev1[k], Hrow[k], S1);
        }

        float T0 = S0, T1 = S1;
        for (int off = 8; off; off >>= 1) {
            T0 += __shfl_xor(T0, off, 16);
            T1 += __shfl_xor(T1, off, 16);
        }
        float n0 = __logf(S0) - __logf(T0);
        float n1 = __logf(S1) - __logf(T1);

        int p = g + r * NGRP;
        __builtin_nontemporal_store(f2bf(n0), msg + (long)(2 * p)     * CC + lane);
        __builtin_nontemporal_store(f2bf(n1), msg + (long)(2 * p + 1) * CC + lane);
    }
}

// ---------------------------------------------------------------------------
// CSR gather + fused update: log_b = log_normalize(sum_in msg + log_b0).
// 16 lanes per node (lane = class). Lanes cooperatively fetch 16 edge ids,
// broadcast via shfl; 16 independent 32B gathers stay in flight.
// ---------------------------------------------------------------------------
__global__ __launch_bounds__(256) void k_agg(
    const unsigned int* __restrict__ row, const unsigned int* __restrict__ csr,
    const unsigned short* __restrict__ msg, const float* __restrict__ logb0,
    float* __restrict__ out)
{
    int idx = blockIdx.x * 256 + threadIdx.x;
    int n = idx >> 4, c = idx & 15;
    unsigned int beg = row[n], end = row[n + 1];

    float acc = 0.f;
    unsigned int base = beg;
    for (; base + 16 <= end; base += 16) {
        int eid = (int)csr[base + c];
#pragma unroll
        for (int j = 0; j < 16; ++j) {
            int e = __shfl(eid, j, 16);
            acc += bf2f(msg[(long)e * CC + c]);
        }
    }
    if (base < end) {
        int cnt = (int)(end - base);
        int eid = (base + c < end) ? (int)csr[base + c] : 0;
        for (int j = 0; j < cnt; ++j) {
            int e = __shfl(eid, j, 16);
            acc += bf2f(msg[(long)e * CC + c]);
        }
    }

    float v = acc + logb0[idx];
    float m = v;
    for (int off = 8; off; off >>= 1) m = fmaxf(m, __shfl_xor(m, off, 16));
    float s = __expf(v - m);
    for (int off = 8; off; off >>= 1) s += __shfl_xor(s, off, 16);
    out[idx] = v - m - __logf(s);
}

// ---------------------------------------------------------------------------
extern "C" void kernel_launch(void* const* d_in, const int* in_sizes, int n_in,
                              void* d_out, int out_size, void* d_ws, size_t ws_size,
                              hipStream_t stream)
{
    const float* x     = (const float*)d_in[0];
    const float* W     = (const float*)d_in[1];
    const float* b     = (const float*)d_in[2];
    const float* param = (const float*)d_in[3];
    const int*   eidx  = (const int*)d_in[4];
    const i2*    esrc2 = (const i2*)eidx;
    const int*   edst  = eidx + EE;

    char* w = (char*)d_ws;
    float*          M      = (float*)w;          w += 256 * 4;
    float*          logb0  = (float*)w;          w += (long)NN * CC * 4;
    float*          logb   = (float*)w;          w += (long)NN * CC * 4;
    unsigned int*   deg    = (unsigned int*)w;   w += (long)NN * 4;
    unsigned int*   rowtmp = (unsigned int*)w;   w += (long)NN * 4;
    unsigned int*   bsum   = (unsigned int*)w;   w += 512 * 4;
    unsigned int*   boff   = (unsigned int*)w;   w += 512 * 4;
    unsigned int*   rowp   = (unsigned int*)w;   w += (long)(NN + 16) * 4;
    unsigned int*   cursor = (unsigned int*)w;   w += (long)NN * 4;
    unsigned int*   csr    = (unsigned int*)w;   w += (long)EE * 4;
    unsigned short* msg    = (unsigned short*)w; // EE*CC bf16 = 51.2 MB

    hipMemsetAsync(deg, 0, (long)NN * 4, stream);
    k_setup   <<<NN * CC / 256, 256, 0, stream>>>(x, W, b, param, edst, M, logb0, deg);
    k_scan_blk<<<NBLK, 256, 0, stream>>>(deg, rowtmp, bsum);
    k_scan_top<<<1, 512, 0, stream>>>(bsum, boff);
    k_scan_add<<<NBLK, 256, 0, stream>>>(rowtmp, boff, rowp, cursor);
    k_csrscat <<<EE / 256, 256, 0, stream>>>(edst, cursor, csr);

    const float* curb = logb0;
    for (int it = 0; it < NITERS; ++it) {
        if (it == 0)
            k_edges_t<false><<<NGRP / 16, 256, 0, stream>>>(esrc2, curb, M, msg);
        else
            k_edges_t<true><<<NGRP / 16, 256, 0, stream>>>(esrc2, curb, M, msg);
        float* dst = (it == NITERS - 1) ? (float*)d_out : logb;
        k_agg<<<NN * CC / 256, 256, 0, stream>>>(rowp, csr, msg, logb0, dst);
        curb = dst;
    }
}

// Round 7
// 576.894 us; speedup vs baseline: 1.3507x; 1.3507x over previous
//
#include <hip/hip_runtime.h>
#include <math.h>

#define NN      100000
#define EE      1600000
#define NPAIRS  800000
#define DIN     128
#define CC      16
#define NITERS  5
#define PPT     4                    // pairs per thread
#define NGRP    (NPAIRS / PPT)       // 200000 groups of 16 lanes
#define NEGLOGC (-2.772588722239781f)
#define FPSCALE 1048576.0f           // 2^20 fixed-point scale
#define FPINV   (1.0f / 1048576.0f)

typedef float  f4 __attribute__((ext_vector_type(4)));
typedef int    i2 __attribute__((ext_vector_type(2)));
typedef unsigned long long ull;

// ---------------------------------------------------------------------------
// helpers: bf16 <-> f32
// ---------------------------------------------------------------------------
__device__ __forceinline__ unsigned short f2bf(float f) {
    unsigned int u = __float_as_uint(f);
    unsigned int r = u + 0x7fffu + ((u >> 16) & 1u);   // round-nearest-even
    return (unsigned short)(r >> 16);
}
__device__ __forceinline__ unsigned int pack_bf(float lo, float hi) {
    return (unsigned int)f2bf(lo) | ((unsigned int)f2bf(hi) << 16);
}

// ---------------------------------------------------------------------------
// fused setup: M = sigmoid(10*param); logb0 = log_softmax(x@W+b); agg = 0
// grid = 6250 blocks of 256 (covers NN*CC == 1.6M exactly)
// ---------------------------------------------------------------------------
__global__ __launch_bounds__(256) void k_setup(
    const float* __restrict__ x, const float* __restrict__ W,
    const float* __restrict__ b, const float* __restrict__ param,
    float* __restrict__ M, float* __restrict__ logb0,
    unsigned int* __restrict__ agg32)
{
    if (blockIdx.x == 0 && threadIdx.x < CC * (CC + 1) / 2) {
        int i = threadIdx.x;
        int r = 0;
        while ((r + 1) * (r + 2) / 2 <= i) ++r;
        int c = i - r * (r + 1) / 2;
        float z = param[i] * 10.0f;
        float s = 1.0f / (1.0f + __expf(-z));
        M[r * CC + c] = s;
        if (r != c) M[c * CC + r] = s;
    }

    int idx = blockIdx.x * 256 + threadIdx.x;
    agg32[idx] = 0u;

    int node = idx >> 4;
    int cls  = idx & 15;
    const f4* xr4 = (const f4*)(x + (long)node * DIN);
    float acc = b[cls];
#pragma unroll 8
    for (int k4 = 0; k4 < DIN / 4; ++k4) {
        f4 xv = __builtin_nontemporal_load(xr4 + k4);   // x streamed once
        acc = fmaf(xv.x, W[(4 * k4 + 0) * CC + cls], acc);
        acc = fmaf(xv.y, W[(4 * k4 + 1) * CC + cls], acc);
        acc = fmaf(xv.z, W[(4 * k4 + 2) * CC + cls], acc);
        acc = fmaf(xv.w, W[(4 * k4 + 3) * CC + cls], acc);
    }
    float m = acc;
    for (int off = 8; off; off >>= 1) m = fmaxf(m, __shfl_xor(m, off, 16));
    float s = __expf(acc - m);
    for (int off = 8; off; off >>= 1) s += __shfl_xor(s, off, 16);
    logb0[idx] = acc - m - __logf(s);
}

// ---------------------------------------------------------------------------
// message update + scatter. 16 lanes per edge-pair (lane = class).
// Linear-space matvec:
//   S[c] = sum_k exp(t[k]) * M[k][c];  log_msg[c] = log S[c] - log(sum_c S[c])
// t in [-log C, ~7] -> exp fp32-safe; no max-subtraction needed.
// msg2[p*16+c] packs pair p both directions as bf16 {lo=edge 2p, hi=2p+1}.
// RD_MSG=false on iter 0 (msg == const -log C); WR_MSG=false on last iter.
//
// Scatter: messages are STRICTLY negative (S < T), so q = round(-n * 2^20)
// is positive; per-node per-class sums < 2^31 -> a packed u64 atomicAdd of
// {q[2j], q[2j+1]<<32} is an exact two-class add (no cross-half carries).
// Even lanes issue edge-0's 8 u64 ops, odd lanes edge-1's: 16 u64 atomics
// per pair instead of 32 f32 atomics -> half the TCC RMW op count.
// Little-endian layout: agg32[n*16+c] ends up holding class c's sum.
// ---------------------------------------------------------------------------
template <bool RD_MSG, bool WR_MSG>
__global__ __launch_bounds__(256) void k_edges_t(
    const i2* __restrict__ esrc2, const i2* __restrict__ edst2,
    const float* __restrict__ logb, const float* __restrict__ Mg,
    unsigned int* __restrict__ msg2, ull* __restrict__ agg8)
{
    __shared__ float sM[CC * CC];
    __shared__ float sE[PPT][16 * 40];   // per-r slice, per-group stride 40
    sM[threadIdx.x] = Mg[threadIdx.x];   // blockDim == 256
    __syncthreads();

    const int lane = threadIdx.x & 15;
    const int gl   = threadIdx.x >> 4;           // group within block (0..15)
    const int g    = blockIdx.x * 16 + gl;       // global group

    float Hrow[CC];                              // M[k][lane] (symmetric)
#pragma unroll
    for (int k = 0; k < CC; ++k) Hrow[k] = sM[k * CC + lane];

    // hoist all streamed loads (independent -> deep pipelining)
    i2 s01[PPT], d01[PPT];
    unsigned int mold[PPT];
#pragma unroll
    for (int r = 0; r < PPT; ++r) {
        int p = g + r * NGRP;
        s01[r] = __builtin_nontemporal_load(esrc2 + p);
        d01[r] = __builtin_nontemporal_load(edst2 + p);
        if (RD_MSG)
            mold[r] = __builtin_nontemporal_load(msg2 + (long)p * CC + lane);
    }

    // exp(t) into per-r LDS slices
#pragma unroll
    for (int r = 0; r < PPT; ++r) {
        float lb0 = logb[(long)s01[r].x * CC + lane];
        float lb1 = logb[(long)s01[r].y * CC + lane];
        float mo0, mo1;
        if (RD_MSG) {
            mo0 = __uint_as_float(mold[r] << 16);          // msg[2p]
            mo1 = __uint_as_float(mold[r] & 0xffff0000u);  // msg[2p+1]
        } else {
            mo0 = NEGLOGC; mo1 = NEGLOGC;
        }
        float* eb = sE[r] + gl * 40;
        eb[lane]      = __expf(lb0 - mo1);   // t = logb[src] - msg[reverse]
        eb[16 + lane] = __expf(lb1 - mo0);
    }

    // matvec + normalize + store + packed-u64 scatter
#pragma unroll
    for (int r = 0; r < PPT; ++r) {
        const float* eb = sE[r] + gl * 40;
        float ev0[CC], ev1[CC];
        *(float4*)(ev0 +  0) = *(const float4*)(eb +  0);
        *(float4*)(ev0 +  4) = *(const float4*)(eb +  4);
        *(float4*)(ev0 +  8) = *(const float4*)(eb +  8);
        *(float4*)(ev0 + 12) = *(const float4*)(eb + 12);
        *(float4*)(ev1 +  0) = *(const float4*)(eb + 16);
        *(float4*)(ev1 +  4) = *(const float4*)(eb + 20);
        *(float4*)(ev1 +  8) = *(const float4*)(eb + 24);
        *(float4*)(ev1 + 12) = *(const float4*)(eb + 28);

        float S0 = 0.f, S1 = 0.f;
#pragma unroll
        for (int k = 0; k < CC; ++k) {
            S0 = fmaf(ev0[k], Hrow[k], S0);
            S1 = fmaf(ev1[k], Hrow[k], S1);
        }

        float T0 = S0, T1 = S1;
        for (int off = 8; off; off >>= 1) {
            T0 += __shfl_xor(T0, off, 16);
            T1 += __shfl_xor(T1, off, 16);
        }
        float n0 = __logf(S0) - __logf(T0);
        float n1 = __logf(S1) - __logf(T1);

        if (WR_MSG) {
            int p = g + r * NGRP;
            __builtin_nontemporal_store(pack_bf(n0, n1),
                                        msg2 + (long)p * CC + lane);
        }

        // fixed-point packed scatter
        unsigned int q0 = (unsigned int)(fmaxf(-n0, 0.f) * FPSCALE + 0.5f);
        unsigned int q1 = (unsigned int)(fmaxf(-n1, 0.f) * FPSCALE + 0.5f);
        unsigned int p0 = __shfl_xor(q0, 1, 16);   // partner class's q
        unsigned int p1 = __shfl_xor(q1, 1, 16);
        bool odd = lane & 1;
        // even lane c=2j: edge0, val = q0(2j) | q0(2j+1)<<32
        // odd  lane c=2j+1: edge1, val = q1(2j) | q1(2j+1)<<32
        ull  val  = odd ? ((ull)p1 | ((ull)q1 << 32))
                        : ((ull)q0 | ((ull)p0 << 32));
        int  node = odd ? d01[r].y : d01[r].x;
        atomicAdd(&agg8[(long)node * 8 + (lane >> 1)], val);
    }
}

// ---------------------------------------------------------------------------
// log_b = log_normalize(agg + log_b0); also resets agg for next iteration.
// agg32[n*16+c] holds the fixed-point class-c sum (little-endian u64 halves).
// ---------------------------------------------------------------------------
__global__ __launch_bounds__(256) void k_update(
    const float* __restrict__ logb0, unsigned int* __restrict__ agg32,
    float* __restrict__ out)
{
    int idx = blockIdx.x * blockDim.x + threadIdx.x;
    unsigned int q = agg32[idx];
    agg32[idx] = 0u;
    float v = fmaf(-(float)q, FPINV, logb0[idx]);
    float m = v;
    for (int off = 8; off; off >>= 1) m = fmaxf(m, __shfl_xor(m, off, 16));
    float s = __expf(v - m);
    for (int off = 8; off; off >>= 1) s += __shfl_xor(s, off, 16);
    out[idx] = v - m - __logf(s);
}

// ---------------------------------------------------------------------------
extern "C" void kernel_launch(void* const* d_in, const int* in_sizes, int n_in,
                              void* d_out, int out_size, void* d_ws, size_t ws_size,
                              hipStream_t stream)
{
    const float* x     = (const float*)d_in[0];
    const float* W     = (const float*)d_in[1];
    const float* b     = (const float*)d_in[2];
    const float* param = (const float*)d_in[3];
    const int*   eidx  = (const int*)d_in[4];
    const i2*    esrc2 = (const i2*)eidx;
    const i2*    edst2 = (const i2*)(eidx + EE);

    float* ws    = (float*)d_ws;
    float* M     = ws;                         // 256 floats
    float* logb0 = M     + 256;                // N*C
    float* logb  = logb0 + (long)NN * CC;      // N*C
    unsigned int* agg32 = (unsigned int*)(logb + (long)NN * CC);  // N*C u32 (u64-aligned)
    ull*          agg8  = (ull*)agg32;
    unsigned int* msg2  = agg32 + (long)NN * CC;                  // NPAIRS*C u32

    k_setup<<<NN * CC / 256, 256, 0, stream>>>(x, W, b, param, M, logb0, agg32);

    const float* curb = logb0;
    for (int it = 0; it < NITERS; ++it) {
        if (it == 0)
            k_edges_t<false, true><<<NGRP / 16, 256, 0, stream>>>(
                esrc2, edst2, curb, M, msg2, agg8);
        else if (it == NITERS - 1)
            k_edges_t<true, false><<<NGRP / 16, 256, 0, stream>>>(
                esrc2, edst2, curb, M, msg2, agg8);
        else
            k_edges_t<true, true><<<NGRP / 16, 256, 0, stream>>>(
                esrc2, edst2, curb, M, msg2, agg8);
        float* dst = (it == NITERS - 1) ? (float*)d_out : logb;
        k_update<<<NN * CC / 256, 256, 0, stream>>>(logb0, agg32, dst);
        curb = dst;
    }
}